// Round 19
// baseline (198.624 us; speedup 1.0000x reference)
//
#include <hip/hip_runtime.h>
#include <stdint.h>

// ============================================================================
// DilatedConv feedback: y_t = y_{t-1} @ A + c_t,  c_t = x[:,:,t+256] @ W1T
// r19 fast path (r17 best config + scan chain-parallelism):
//   cgemm_m : v5d (r17-proven best, 79us, RNE rounding): 128-t tiles,
//             (512,2) 256-VGPR budget keeps bv[8][2] register-resident;
//             64 staging loads in one in-flight group.
//   scan2   : OUT_L 32->16 (WARM=20 unchanged): 496 chains of 36 steps
//             instead of 248 chains of 52. Chains are latency-bound serial
//             (540ns/step at <1 block/CU); doubling co-resident chains
//             shortens the critical chain 52->36 steps.
//   yout    : v3 r12-proven OUT-ALIGNED transpose, full-line f32 writes.
// Runtime ws_size guard: falls back to round-1 VALU path if ws too small.
// ============================================================================

constexpr int BATCH  = 16;
constexpr int CH     = 256;
constexpr int NEL    = 8192;
constexpr int NDIL   = 256;
constexpr int TSTEPS = NEL - (NDIL + 1);          // 7935
constexpr int LCH    = 16;                         // fallback chunking
constexpr int NCH    = (TSTEPS + LCH - 1) / LCH;   // 496 (fallback)
constexpr int OUT_L  = 16;                         // scan2 output span
constexpr int WARM   = 20;                         // scan2 warm-up steps
constexpr int NCH2   = (TSTEPS + OUT_L - 1) / OUT_L;  // 496
constexpr int TPB    = 256;
constexpr int YPAD   = 260;                        // fallback scan state pad
constexpr int A2PAD  = 264;
constexpr int TTILES = (TSTEPS + 127) / 128;       // 62
constexpr int YROW   = 264;                        // bf16 state row (pad)

// workspace offsets (bytes)
constexpr size_t OFF_AF    = 0;
constexpr size_t OFF_P1    = OFF_AF    + 256 * 1024;
constexpr size_t OFF_P2    = OFF_P1    + 256 * 1024;
constexpr size_t OFF_AB16  = OFF_P2    + 256 * 1024;
constexpr size_t OFF_W1B   = OFF_AB16  + 128 * 1024;
constexpr size_t OFF_E     = OFF_W1B   + 128 * 1024;
constexpr size_t OFF_INIT  = OFF_E     + (size_t)NCH * BATCH * CH * 4;
constexpr size_t OFF_AFRAG = OFF_INIT  + (size_t)(NCH + 1) * BATCH * CH * 4;
constexpr size_t OFF_W1FR  = OFF_AFRAG + 128 * 1024;
constexpr size_t OFF_CBUF  = OFF_W1FR  + 128 * 1024;
constexpr size_t CBUF_BYTES = (size_t)(NCH * LCH) * BATCH * CH * 2;  // 65MB
constexpr size_t OFF_YBUF  = OFF_CBUF + CBUF_BYTES;
constexpr size_t WS_NEED   = OFF_YBUF + CBUF_BYTES;                  // ~155MB

typedef __attribute__((ext_vector_type(8))) short bf16x8;
typedef __attribute__((ext_vector_type(4))) float f32x4;

__device__ __forceinline__ float bfu(uint32_t hibits) { return __uint_as_float(hibits); }
__device__ __forceinline__ float bf2f(uint16_t b) { return __uint_as_float(((uint32_t)b) << 16); }
__device__ __forceinline__ uint16_t f2bf(float f) {          // RNE float->bf16
  uint32_t u = __float_as_uint(f);
  uint32_t r = u + 0x7fffu + ((u >> 16) & 1u);
  return (uint16_t)(r >> 16);
}

// ---------------------------------------------------------------- prep weights
// Afrag/W1frag = B-fragment-ordered (validated layout):
// frag(kb,nt): lane l, elem i  <=  M[kb*32 + (l>>4)*8 + i][nt*16 + (l&15)]
__global__ void k_prep(const float* __restrict__ w, float* __restrict__ Af,
                       uint16_t* __restrict__ Ab, uint16_t* __restrict__ W1b,
                       uint16_t* __restrict__ Afrag, uint16_t* __restrict__ W1f) {
  int o = blockIdx.x, c = threadIdx.x;
  const float2 wv = *(const float2*)&w[(size_t)(o * CH + c) * 2];
  Af[c * CH + o]  = wv.x;
  Ab[c * CH + o]  = f2bf(wv.x);
  W1b[c * CH + o] = f2bf(wv.y);
  if (Afrag) {
    int kb = c >> 5, g = (c >> 3) & 3, ii = c & 7;
    int nt = o >> 4, mm = o & 15;
    size_t idx = (((size_t)(kb * 16 + nt) * 64) + (g * 16 + mm)) * 8 + ii;
    Afrag[idx] = f2bf(wv.x);
    W1f[idx]   = f2bf(wv.y);
  }
}

__global__ void k_init0(const float* __restrict__ x, float* __restrict__ initbuf) {
  int b = blockIdx.x, c = threadIdx.x;
  initbuf[b * CH + c] = x[(size_t)(b * CH + c) * NEL];
}

__global__ __launch_bounds__(TPB) void k_sqmm(const float* __restrict__ in,
                                              float* __restrict__ outm) {
  __shared__ __align__(16) float row[CH];
  int r = blockIdx.x, o = threadIdx.x;
  row[o] = in[r * CH + o];
  __syncthreads();
  float acc = 0.f;
#pragma unroll 8
  for (int k = 0; k < CH; ++k) acc += row[k] * in[k * CH + o];
  outm[r * CH + o] = acc;
}

__global__ void k_edges(const float* __restrict__ x, float* __restrict__ out) {
  size_t base = (size_t)blockIdx.x * NEL;
  int t = threadIdx.x;
  out[base + (NEL - 256) + t] = x[base + (NEL - 256) + t];
  if (t == 0) out[base] = x[base];
}

// ------------------- MFMA cGEMM v5d (r17-proven): cbuf[t][b*256+o] bf16
// Block 512 thr (8 waves), tile 128t x 256o, one b. launch_bounds(512,2):
// 256-VGPR budget keeps bv[8][2] register-resident.
// All 64 staging loads issued in one group.
__global__ __launch_bounds__(512, 2) void k_cgemm_m(const float* __restrict__ x,
                                                    const uint16_t* __restrict__ W1f,
                                                    uint16_t* __restrict__ cb) {
  __shared__ __align__(16) uint16_t Axs[64 * 64 * 8];  // [mt*8+kb][lane][8] 64KB
  int tid = threadIdx.x, bid = blockIdx.x;
  int b = bid / TTILES, tt = bid % TTILES;
  int t0 = tt * 128;
  int w = tid >> 6, l = tid & 63, lm = l & 15, g = l >> 4;
  const float* xb = x + (size_t)b * CH * NEL + (t0 + NDIL);

  bf16x8 bv[8][2];
#pragma unroll
  for (int kb = 0; kb < 8; ++kb)
#pragma unroll
    for (int p = 0; p < 2; ++p)
      bv[kb][p] =
          *(const bf16x8*)&W1f[(((size_t)(kb * 16 + w * 2 + p) * 64) + l) * 8];

  int tA = w * 16 + lm;
  {  // stage: all 64 loads in flight, then pack+write
    float v[8][8];
#pragma unroll
    for (int k2 = 0; k2 < 8; ++k2)
#pragma unroll
      for (int i = 0; i < 8; ++i)
        v[k2][i] = xb[(size_t)(k2 * 32 + g * 8 + i) * NEL + tA];
#pragma unroll
    for (int k2 = 0; k2 < 8; ++k2) {
      uint4 pk;
      pk.x = (uint32_t)f2bf(v[k2][0]) | ((uint32_t)f2bf(v[k2][1]) << 16);
      pk.y = (uint32_t)f2bf(v[k2][2]) | ((uint32_t)f2bf(v[k2][3]) << 16);
      pk.z = (uint32_t)f2bf(v[k2][4]) | ((uint32_t)f2bf(v[k2][5]) << 16);
      pk.w = (uint32_t)f2bf(v[k2][6]) | ((uint32_t)f2bf(v[k2][7]) << 16);
      *(uint4*)&Axs[((w * 8 + k2) * 64 + l) * 8] = pk;
    }
  }
  __syncthreads();

#pragma unroll 1
  for (int mt = 0; mt < 8; ++mt) {
    f32x4 acc0 = (f32x4)0.f, acc1 = (f32x4)0.f;
#pragma unroll
    for (int kb = 0; kb < 8; ++kb) {
      bf16x8 av = *(const bf16x8*)&Axs[((mt * 8 + kb) * 64 + l) * 8];
      acc0 = __builtin_amdgcn_mfma_f32_16x16x32_bf16(av, bv[kb][0], acc0, 0, 0, 0);
      acc1 = __builtin_amdgcn_mfma_f32_16x16x32_bf16(av, bv[kb][1], acc1, 0, 0, 0);
    }
#pragma unroll
    for (int r = 0; r < 4; ++r) {
      int t2 = t0 + mt * 16 + g * 4 + r;
      if (t2 < TSTEPS) {
        size_t base = (size_t)t2 * (BATCH * CH) + b * CH;
        cb[base + (w * 2 + 0) * 16 + lm] = f2bf(acc0[r]);
        cb[base + (w * 2 + 1) * 16 + lm] = f2bf(acc1[r]);
      }
    }
  }
}

// ------------------- scan2: overlapped warm-up scan (r11-proven; OUT_L=16)
__device__ __forceinline__ void scan2_step(
    int t, bool pref, bool doout, const uint16_t* Yr, uint16_t* Yw,
    const uint16_t* __restrict__ cb, uint16_t* __restrict__ yb,
    const bf16x8 af[8][4], ushort* cc, int w, int lm, int g, int tid) {
  bf16x8 yv[8];
#pragma unroll
  for (int kb = 0; kb < 8; ++kb)
    yv[kb] = *(const bf16x8*)&Yr[lm * YROW + kb * 32 + g * 8];
  f32x4 acc[4];
#pragma unroll
  for (int ntl = 0; ntl < 4; ++ntl)
#pragma unroll
    for (int r = 0; r < 4; ++r)
      acc[ntl][r] = bfu(((uint32_t)cc[ntl * 4 + r]) << 16);
  if (pref) {  // c_{t+2} into same regs (2 steps of slack)
    size_t cbase = (size_t)(t + 2) * (BATCH * CH);
#pragma unroll
    for (int ntl = 0; ntl < 4; ++ntl)
#pragma unroll
      for (int r = 0; r < 4; ++r)
        cc[ntl * 4 + r] = cb[cbase + (g * 4 + r) * CH + (w * 4 + ntl) * 16 + lm];
  }
#pragma unroll
  for (int ntl = 0; ntl < 4; ++ntl) {
#pragma unroll
    for (int kb = 0; kb < 8; ++kb)
      acc[ntl] = __builtin_amdgcn_mfma_f32_16x16x32_bf16(yv[kb], af[kb][ntl], acc[ntl], 0, 0, 0);
  }
  uint16_t hbv[16];
#pragma unroll
  for (int ntl = 0; ntl < 4; ++ntl)
#pragma unroll
    for (int r = 0; r < 4; ++r) {
      float v = acc[ntl][r];
      int bb = g * 4 + r, o = (w * 4 + ntl) * 16 + lm;
      uint16_t hb = f2bf(v);
      hbv[ntl * 4 + r] = hb;
      Yw[bb * YROW + o] = hb;
    }
  if (doout) {  // fragment-contiguous y (2 coalesced uint4; fly over barrier)
    uint4 p0, p1;
    p0.x = (uint32_t)hbv[0] | ((uint32_t)hbv[1] << 16);
    p0.y = (uint32_t)hbv[2] | ((uint32_t)hbv[3] << 16);
    p0.z = (uint32_t)hbv[4] | ((uint32_t)hbv[5] << 16);
    p0.w = (uint32_t)hbv[6] | ((uint32_t)hbv[7] << 16);
    p1.x = (uint32_t)hbv[8] | ((uint32_t)hbv[9] << 16);
    p1.y = (uint32_t)hbv[10] | ((uint32_t)hbv[11] << 16);
    p1.z = (uint32_t)hbv[12] | ((uint32_t)hbv[13] << 16);
    p1.w = (uint32_t)hbv[14] | ((uint32_t)hbv[15] << 16);
    uint4* dst = (uint4*)&yb[(size_t)t * 4096 + tid * 16];
    dst[0] = p0;
    dst[1] = p1;
  }
  asm volatile("s_waitcnt lgkmcnt(0)" ::: "memory");
  __builtin_amdgcn_sched_barrier(0);
  __builtin_amdgcn_s_barrier();
  __builtin_amdgcn_sched_barrier(0);
}

__global__ __launch_bounds__(TPB, 2) void k_scan2(
    const uint16_t* __restrict__ Afrag, const uint16_t* __restrict__ cb,
    uint16_t* __restrict__ yb, const float* __restrict__ x) {
  __shared__ __align__(16) uint16_t Y[2][16 * YROW];
  int tid = threadIdx.x;
  int j = blockIdx.x;
  int w = tid >> 6, l = tid & 63;
  int lm = l & 15, g = l >> 4;

  bf16x8 af[8][4];
#pragma unroll
  for (int kb = 0; kb < 8; ++kb)
#pragma unroll
    for (int ntl = 0; ntl < 4; ++ntl) {
      int nt = w * 4 + ntl;
      af[kb][ntl] = *(const bf16x8*)&Afrag[(((size_t)(kb * 16 + nt) * 64) + l) * 8];
    }

  int tstart   = (j == 0) ? 0 : OUT_L * j - WARM;
  int outstart = OUT_L * j;
  int tend     = min(OUT_L * (j + 1), TSTEPS);

  if (j == 0) {  // exact init: Y = x[:,:,0]
    int b = tid >> 4, o0 = (tid & 15) * 16;
#pragma unroll
    for (int q = 0; q < 16; ++q)
      Y[0][b * YROW + o0 + q] = f2bf(x[(size_t)(b * CH + o0 + q) * NEL]);
  } else {
    for (int q = tid; q < 16 * YROW; q += TPB) Y[0][q] = 0;
  }

  ushort c0[16], c1[16];
  {  // prologue: c at tstart, tstart+1
#pragma unroll
    for (int ntl = 0; ntl < 4; ++ntl)
#pragma unroll
      for (int r = 0; r < 4; ++r) {
        size_t off = (size_t)(g * 4 + r) * CH + (w * 4 + ntl) * 16 + lm;
        c0[ntl * 4 + r] = cb[(size_t)tstart * (BATCH * CH) + off];
        c1[ntl * 4 + r] = cb[(size_t)(tstart + 1) * (BATCH * CH) + off];
      }
  }
  __syncthreads();

#pragma unroll 1
  for (int ii = 0; ii < OUT_L + WARM + 2; ii += 2) {
    int t = tstart + ii;
    if (t >= tend) break;
    scan2_step(t, t + 2 < tend, t >= outstart, Y[0], Y[1], cb, yb,
               af, c0, w, lm, g, tid);
    if (t + 1 >= tend) break;
    scan2_step(t + 1, t + 3 < tend, t + 1 >= outstart, Y[1], Y[0], cb, yb,
               af, c1, w, lm, g, tid);
  }
}

// ------------------- yout v3 (r12-proven): OUT-ALIGNED blocks -> out f32
__global__ __launch_bounds__(TPB) void k_yout(const uint16_t* __restrict__ yb,
                                              float* __restrict__ out) {
  __shared__ __align__(16) uint16_t t2[256 * 72];  // 36.9KB
  int bid = blockIdx.x;
  int tb = bid >> 4, sub = bid & 15;
  int G = sub >> 2, wS = sub & 3;
  int t0 = tb * 64;  // OUT index base (aligned); 124*64 = 7936 exact cover
  int tid = threadIdx.x;
  {  // load: row tl holds y[t0+tl-1]; scatter u16 into [col][t]
    int tl = tid >> 2, part = tid & 3;
    int ty = t0 + tl - 1;
    if (ty >= 0) {
      const uint16_t* src =
          &yb[(size_t)ty * 4096 + (wS * 64 + G * 16) * 16 + part * 64];
#pragma unroll
      for (int i = 0; i < 8; ++i) {
        uint4 vv = *(const uint4*)&src[i * 8];
        uint32_t uu[4] = {vv.x, vv.y, vv.z, vv.w};
        int colb = part * 64 + i * 8;
#pragma unroll
        for (int e = 0; e < 4; ++e) {
          t2[(colb + 2 * e) * 72 + tl]     = (uint16_t)(uu[e] & 0xffffu);
          t2[(colb + 2 * e + 1) * 72 + tl] = (uint16_t)(uu[e] >> 16);
        }
      }
    }
  }
  __syncthreads();
  {  // store: thread -> one (b,o); out[t0+q] = y[t0+q-1] = t2[col][q]; aligned
    int b = G * 4 + (tid >> 6);
    int o = wS * 64 + (tid & 63);
    int col = (o & 15) * 16 + ((o >> 4) & 3) * 4 + (b & 3);
    float* dst = &out[(size_t)(b * CH + o) * NEL + t0];
#pragma unroll
    for (int k4 = 0; k4 < 4; ++k4) {
      uint4 v0 = *(const uint4*)&t2[col * 72 + k4 * 16];
      uint4 v1 = *(const uint4*)&t2[col * 72 + k4 * 16 + 8];
      uint32_t uu[8] = {v0.x, v0.y, v0.z, v0.w, v1.x, v1.y, v1.z, v1.w};
      float f[16];
#pragma unroll
      for (int e = 0; e < 8; ++e) {
        f[2 * e]     = bfu(uu[e] << 16);
        f[2 * e + 1] = bfu(uu[e] & 0xffff0000u);
      }
      if (tb == 0 && k4 == 0) {  // skip out idx 0 (edges wrote x0)
#pragma unroll
        for (int e = 1; e < 16; ++e) dst[e] = f[e];
      } else {
#pragma unroll
        for (int m = 0; m < 4; ++m)
          *(float4*)&dst[k4 * 16 + m * 4] =
              make_float4(f[4 * m], f[4 * m + 1], f[4 * m + 2], f[4 * m + 3]);
      }
    }
  }
}

// ======================= fallback path (round-1, proven) =====================
__global__ __launch_bounds__(TPB) void k_cgemm_v(const float* __restrict__ x,
                                                 const uint16_t* __restrict__ W1b,
                                                 float* __restrict__ out) {
  __shared__ __align__(16) uint16_t w1[CH * 128];
  __shared__ __align__(16) float xs[32][128];
  int tid = threadIdx.x;
  int bid = blockIdx.x;
  int b = bid / (TTILES * 2);
  int rem = bid % (TTILES * 2);
  int ttile = rem >> 1, otile = rem & 1;
  int t0 = ttile * 128, o0 = otile * 128;
  int tx = tid & 15, ty = tid >> 4;
  int o8 = o0 + tx * 8;
  int tb = t0 + ty * 8;
  {
    uint4* dst = (uint4*)w1;
    for (int q = tid; q < CH * 128 / 8; q += TPB) {
      int row = q >> 4, seg = q & 15;
      dst[q] = *(const uint4*)&W1b[row * CH + o0 + seg * 8];
    }
  }
  float acc[8][8];
#pragma unroll
  for (int i = 0; i < 8; ++i)
#pragma unroll
    for (int j = 0; j < 8; ++j) acc[i][j] = 0.f;
  for (int c0 = 0; c0 < CH; c0 += 32) {
    __syncthreads();
#pragma unroll
    for (int kk = 0; kk < 4; ++kk) {
      int q = tid + kk * TPB;
      int cc = q >> 5, tf = (q & 31) * 4;
      *(float4*)&xs[cc][tf] =
          *(const float4*)&x[(size_t)(b * CH + c0 + cc) * NEL + t0 + NDIL + tf];
    }
    __syncthreads();
#pragma unroll 4
    for (int cc = 0; cc < 32; ++cc) {
      float4 xa = *(const float4*)&xs[cc][ty * 8];
      float4 xb = *(const float4*)&xs[cc][ty * 8 + 4];
      float xv[8] = {xa.x, xa.y, xa.z, xa.w, xb.x, xb.y, xb.z, xb.w};
      uint4 wv = *(const uint4*)&w1[(c0 + cc) * 128 + tx * 8];
      float wf[8] = {bfu(wv.x << 16), bfu(wv.x & 0xffff0000u),
                     bfu(wv.y << 16), bfu(wv.y & 0xffff0000u),
                     bfu(wv.z << 16), bfu(wv.z & 0xffff0000u),
                     bfu(wv.w << 16), bfu(wv.w & 0xffff0000u)};
#pragma unroll
      for (int i = 0; i < 8; ++i)
#pragma unroll
        for (int j = 0; j < 8; ++j) acc[i][j] += xv[i] * wf[j];
    }
  }
#pragma unroll
  for (int j = 0; j < 8; ++j) {
    size_t base = (size_t)(b * CH + o8 + j) * NEL + tb + 1;
#pragma unroll
    for (int i = 0; i < 8; ++i)
      if (tb + i < TSTEPS) out[base + i] = acc[i][j];
  }
}

template <bool PH3>
__global__ __launch_bounds__(TPB) void k_scan(const uint16_t* __restrict__ Ab,
                                              const float* __restrict__ initbuf,
                                              float* __restrict__ Ebuf,
                                              float* __restrict__ out) {
  __shared__ __align__(16) uint16_t Al[CH * CH];
  __shared__ __align__(16) float yl[BATCH * YPAD];
  int tid = threadIdx.x;
  int j = blockIdx.x;
  {
    const uint4* src = (const uint4*)Ab;
    uint4* dst = (uint4*)Al;
    for (int q = tid; q < CH * CH / 8; q += TPB) dst[q] = src[q];
  }
  if constexpr (PH3) {
    for (int q = tid; q < BATCH * CH / 4; q += TPB) {
      int b = q >> 6, c4 = (q & 63) * 4;
      *(float4*)&yl[b * YPAD + c4] =
          *(const float4*)&initbuf[(size_t)j * BATCH * CH + b * CH + c4];
    }
  } else {
    for (int q = tid; q < BATCH * YPAD; q += TPB) yl[q] = 0.f;
  }
  __syncthreads();
  int o4 = (tid & 63) * 4;
  int b4 = (tid >> 6) * 4;
  int len = min(LCH, TSTEPS - j * LCH);
  float acc[4][4];
  for (int i = 0; i < len; ++i) {
    int t = j * LCH + i;
    float cv[4][4];
#pragma unroll
    for (int bb = 0; bb < 4; ++bb)
#pragma unroll
      for (int oo = 0; oo < 4; ++oo)
        cv[bb][oo] = out[(size_t)((b4 + bb) * CH + o4 + oo) * NEL + t + 1];
#pragma unroll
    for (int bb = 0; bb < 4; ++bb)
#pragma unroll
      for (int oo = 0; oo < 4; ++oo) acc[bb][oo] = 0.f;
#pragma unroll 2
    for (int c = 0; c < CH; c += 4) {
      float4 v0 = *(const float4*)&yl[(b4 + 0) * YPAD + c];
      float4 v1 = *(const float4*)&yl[(b4 + 1) * YPAD + c];
      float4 v2 = *(const float4*)&yl[(b4 + 2) * YPAD + c];
      float4 v3 = *(const float4*)&yl[(b4 + 3) * YPAD + c];
      float y0[4] = {v0.x, v0.y, v0.z, v0.w};
      float y1[4] = {v1.x, v1.y, v1.z, v1.w};
      float y2[4] = {v2.x, v2.y, v2.z, v2.w};
      float y3[4] = {v3.x, v3.y, v3.z, v3.w};
#pragma unroll
      for (int k = 0; k < 4; ++k) {
        uint2 au = *(const uint2*)&Al[(c + k) * CH + o4];
        float a[4] = {bfu(au.x << 16), bfu(au.x & 0xffff0000u),
                      bfu(au.y << 16), bfu(au.y & 0xffff0000u)};
#pragma unroll
        for (int oo = 0; oo < 4; ++oo) {
          acc[0][oo] += y0[k] * a[oo];
          acc[1][oo] += y1[k] * a[oo];
          acc[2][oo] += y2[k] * a[oo];
          acc[3][oo] += y3[k] * a[oo];
        }
      }
    }
#pragma unroll
    for (int bb = 0; bb < 4; ++bb)
#pragma unroll
      for (int oo = 0; oo < 4; ++oo) acc[bb][oo] += cv[bb][oo];
    __syncthreads();
#pragma unroll
    for (int bb = 0; bb < 4; ++bb)
      *(float4*)&yl[(b4 + bb) * YPAD + o4] =
          make_float4(acc[bb][0], acc[bb][1], acc[bb][2], acc[bb][3]);
    if constexpr (PH3) {
#pragma unroll
      for (int bb = 0; bb < 4; ++bb)
#pragma unroll
        for (int oo = 0; oo < 4; ++oo)
          out[(size_t)((b4 + bb) * CH + o4 + oo) * NEL + t + 1] = acc[bb][oo];
    }
    __syncthreads();
  }
  if constexpr (!PH3) {
#pragma unroll
    for (int bb = 0; bb < 4; ++bb)
#pragma unroll
      for (int oo = 0; oo < 4; ++oo)
        Ebuf[(size_t)j * BATCH * CH + (b4 + bb) * CH + o4 + oo] = acc[bb][oo];
  }
}

__global__ __launch_bounds__(TPB) void k_phase2(const float* __restrict__ ALf,
                                                const float* __restrict__ Ebuf,
                                                float* __restrict__ initbuf) {
  __shared__ __align__(16) uint16_t At[CH * A2PAD];
  __shared__ __align__(16) float st[CH];
  int b = blockIdx.x, tid = threadIdx.x;
  for (int q = tid; q < CH * CH; q += TPB) {
    int c = q >> 8, o = q & 255;
    At[o * A2PAD + c] = f2bf(ALf[q]);
  }
  st[tid] = initbuf[b * CH + tid];
  __syncthreads();
  for (int jj = 1; jj < NCH; ++jj) {
    float acc = Ebuf[(size_t)(jj - 1) * BATCH * CH + b * CH + tid];
#pragma unroll 4
    for (int c = 0; c < CH; c += 8) {
      uint4 au = *(const uint4*)&At[tid * A2PAD + c];
      float4 s0 = *(const float4*)&st[c];
      float4 s1 = *(const float4*)&st[c + 4];
      acc += bfu(au.x << 16) * s0.x + bfu(au.x & 0xffff0000u) * s0.y +
             bfu(au.y << 16) * s0.z + bfu(au.y & 0xffff0000u) * s0.w +
             bfu(au.z << 16) * s1.x + bfu(au.z & 0xffff0000u) * s1.y +
             bfu(au.w << 16) * s1.z + bfu(au.w & 0xffff0000u) * s1.w;
    }
    __syncthreads();
    st[tid] = acc;
    initbuf[(size_t)jj * BATCH * CH + b * CH + tid] = acc;
    __syncthreads();
  }
}

// ============================================================================
extern "C" void kernel_launch(void* const* d_in, const int* in_sizes, int n_in,
                              void* d_out, int out_size, void* d_ws, size_t ws_size,
                              hipStream_t stream) {
  const float* x = (const float*)d_in[0];
  const float* w = (const float*)d_in[1];
  float* out = (float*)d_out;
  char* ws = (char*)d_ws;

  float*    Af    = (float*)(ws + OFF_AF);
  float*    P1    = (float*)(ws + OFF_P1);
  float*    P2    = (float*)(ws + OFF_P2);
  uint16_t* Ab    = (uint16_t*)(ws + OFF_AB16);
  uint16_t* W1b   = (uint16_t*)(ws + OFF_W1B);
  float*    Ebuf  = (float*)(ws + OFF_E);
  float*    inb   = (float*)(ws + OFF_INIT);
  uint16_t* Afrag = (uint16_t*)(ws + OFF_AFRAG);
  uint16_t* W1f   = (uint16_t*)(ws + OFF_W1FR);
  uint16_t* cbuf  = (uint16_t*)(ws + OFF_CBUF);
  uint16_t* ybuf  = (uint16_t*)(ws + OFF_YBUF);

  const bool fast = ws_size >= WS_NEED;

  k_prep<<<CH, CH, 0, stream>>>(w, Af, Ab, W1b, fast ? Afrag : nullptr, W1f);
  if (fast) {
    k_edges<<<BATCH * CH, 256, 0, stream>>>(x, out);
    k_cgemm_m<<<BATCH * TTILES, 512, 0, stream>>>(x, W1f, cbuf);
    k_scan2<<<NCH2, TPB, 0, stream>>>(Afrag, cbuf, ybuf, x);
    k_yout<<<124 * 16, TPB, 0, stream>>>(ybuf, out);
  } else {
    k_edges<<<BATCH * CH, 256, 0, stream>>>(x, out);
    k_init0<<<BATCH, CH, 0, stream>>>(x, inb);
    k_sqmm<<<CH, TPB, 0, stream>>>(Af, P1);   // A^2
    k_sqmm<<<CH, TPB, 0, stream>>>(P1, P2);   // A^4
    k_sqmm<<<CH, TPB, 0, stream>>>(P2, P1);   // A^8
    k_sqmm<<<CH, TPB, 0, stream>>>(P1, P2);   // A^16 (= A^LCH)
    k_cgemm_v<<<BATCH * TTILES * 2, TPB, 0, stream>>>(x, W1b, out);
    k_scan<false><<<NCH - 1, TPB, 0, stream>>>(Ab, nullptr, Ebuf, out);
    k_phase2<<<BATCH, TPB, 0, stream>>>(P2, Ebuf, inb);
    k_scan<true><<<NCH, TPB, 0, stream>>>(Ab, inb, nullptr, out);
  }
}

// Round 20
// 188.947 us; speedup vs baseline: 1.0512x; 1.0512x over previous
//
#include <hip/hip_runtime.h>
#include <stdint.h>

// ============================================================================
// DilatedConv feedback: y_t = y_{t-1} @ A + c_t,  c_t = x[:,:,t+256] @ W1T
// r20 = r17 exact (measured best: 189.3us, absmax 0.03125).
//   cgemm_m : v5d: 128-t tiles, (512,2) 256-VGPR budget keeps bv[8][2]
//             register-resident; 64 staging loads in one in-flight group.
//   scan2   : overlapped warm-up scan, OUT_L=32/WARM=20 (r19 falsified both
//             directions of OUT_L change -> this is the optimum).
//   yout    : v3 OUT-ALIGNED transpose, full-line f32 writes.
// Runtime ws_size guard: falls back to round-1 VALU path if ws too small.
// ============================================================================

constexpr int BATCH  = 16;
constexpr int CH     = 256;
constexpr int NEL    = 8192;
constexpr int NDIL   = 256;
constexpr int TSTEPS = NEL - (NDIL + 1);          // 7935
constexpr int LCH    = 16;                         // fallback chunking
constexpr int NCH    = (TSTEPS + LCH - 1) / LCH;   // 496 (fallback)
constexpr int OUT_L  = 32;                         // scan2 output span
constexpr int WARM   = 20;                         // scan2 warm-up steps
constexpr int NCH2   = (TSTEPS + OUT_L - 1) / OUT_L;  // 248
constexpr int TPB    = 256;
constexpr int YPAD   = 260;                        // fallback scan state pad
constexpr int A2PAD  = 264;
constexpr int TTILES = (TSTEPS + 127) / 128;       // 62
constexpr int YROW   = 264;                        // bf16 state row (pad)

// workspace offsets (bytes)
constexpr size_t OFF_AF    = 0;
constexpr size_t OFF_P1    = OFF_AF    + 256 * 1024;
constexpr size_t OFF_P2    = OFF_P1    + 256 * 1024;
constexpr size_t OFF_AB16  = OFF_P2    + 256 * 1024;
constexpr size_t OFF_W1B   = OFF_AB16  + 128 * 1024;
constexpr size_t OFF_E     = OFF_W1B   + 128 * 1024;
constexpr size_t OFF_INIT  = OFF_E     + (size_t)NCH * BATCH * CH * 4;
constexpr size_t OFF_AFRAG = OFF_INIT  + (size_t)(NCH + 1) * BATCH * CH * 4;
constexpr size_t OFF_W1FR  = OFF_AFRAG + 128 * 1024;
constexpr size_t OFF_CBUF  = OFF_W1FR  + 128 * 1024;
constexpr size_t CBUF_BYTES = (size_t)(NCH * LCH) * BATCH * CH * 2;  // 65MB
constexpr size_t OFF_YBUF  = OFF_CBUF + CBUF_BYTES;
constexpr size_t WS_NEED   = OFF_YBUF + CBUF_BYTES;                  // ~155MB

typedef __attribute__((ext_vector_type(8))) short bf16x8;
typedef __attribute__((ext_vector_type(4))) float f32x4;

__device__ __forceinline__ float bfu(uint32_t hibits) { return __uint_as_float(hibits); }
__device__ __forceinline__ float bf2f(uint16_t b) { return __uint_as_float(((uint32_t)b) << 16); }
__device__ __forceinline__ uint16_t f2bf(float f) {          // RNE float->bf16
  uint32_t u = __float_as_uint(f);
  uint32_t r = u + 0x7fffu + ((u >> 16) & 1u);
  return (uint16_t)(r >> 16);
}

// ---------------------------------------------------------------- prep weights
// Afrag/W1frag = B-fragment-ordered (validated layout):
// frag(kb,nt): lane l, elem i  <=  M[kb*32 + (l>>4)*8 + i][nt*16 + (l&15)]
__global__ void k_prep(const float* __restrict__ w, float* __restrict__ Af,
                       uint16_t* __restrict__ Ab, uint16_t* __restrict__ W1b,
                       uint16_t* __restrict__ Afrag, uint16_t* __restrict__ W1f) {
  int o = blockIdx.x, c = threadIdx.x;
  const float2 wv = *(const float2*)&w[(size_t)(o * CH + c) * 2];
  Af[c * CH + o]  = wv.x;
  Ab[c * CH + o]  = f2bf(wv.x);
  W1b[c * CH + o] = f2bf(wv.y);
  if (Afrag) {
    int kb = c >> 5, g = (c >> 3) & 3, ii = c & 7;
    int nt = o >> 4, mm = o & 15;
    size_t idx = (((size_t)(kb * 16 + nt) * 64) + (g * 16 + mm)) * 8 + ii;
    Afrag[idx] = f2bf(wv.x);
    W1f[idx]   = f2bf(wv.y);
  }
}

__global__ void k_init0(const float* __restrict__ x, float* __restrict__ initbuf) {
  int b = blockIdx.x, c = threadIdx.x;
  initbuf[b * CH + c] = x[(size_t)(b * CH + c) * NEL];
}

__global__ __launch_bounds__(TPB) void k_sqmm(const float* __restrict__ in,
                                              float* __restrict__ outm) {
  __shared__ __align__(16) float row[CH];
  int r = blockIdx.x, o = threadIdx.x;
  row[o] = in[r * CH + o];
  __syncthreads();
  float acc = 0.f;
#pragma unroll 8
  for (int k = 0; k < CH; ++k) acc += row[k] * in[k * CH + o];
  outm[r * CH + o] = acc;
}

__global__ void k_edges(const float* __restrict__ x, float* __restrict__ out) {
  size_t base = (size_t)blockIdx.x * NEL;
  int t = threadIdx.x;
  out[base + (NEL - 256) + t] = x[base + (NEL - 256) + t];
  if (t == 0) out[base] = x[base];
}

// ------------------- MFMA cGEMM v5d (r17-proven): cbuf[t][b*256+o] bf16
// Block 512 thr (8 waves), tile 128t x 256o, one b. launch_bounds(512,2):
// 256-VGPR budget keeps bv[8][2] register-resident.
// All 64 staging loads issued in one group.
__global__ __launch_bounds__(512, 2) void k_cgemm_m(const float* __restrict__ x,
                                                    const uint16_t* __restrict__ W1f,
                                                    uint16_t* __restrict__ cb) {
  __shared__ __align__(16) uint16_t Axs[64 * 64 * 8];  // [mt*8+kb][lane][8] 64KB
  int tid = threadIdx.x, bid = blockIdx.x;
  int b = bid / TTILES, tt = bid % TTILES;
  int t0 = tt * 128;
  int w = tid >> 6, l = tid & 63, lm = l & 15, g = l >> 4;
  const float* xb = x + (size_t)b * CH * NEL + (t0 + NDIL);

  bf16x8 bv[8][2];
#pragma unroll
  for (int kb = 0; kb < 8; ++kb)
#pragma unroll
    for (int p = 0; p < 2; ++p)
      bv[kb][p] =
          *(const bf16x8*)&W1f[(((size_t)(kb * 16 + w * 2 + p) * 64) + l) * 8];

  int tA = w * 16 + lm;
  {  // stage: all 64 loads in flight, then pack+write
    float v[8][8];
#pragma unroll
    for (int k2 = 0; k2 < 8; ++k2)
#pragma unroll
      for (int i = 0; i < 8; ++i)
        v[k2][i] = xb[(size_t)(k2 * 32 + g * 8 + i) * NEL + tA];
#pragma unroll
    for (int k2 = 0; k2 < 8; ++k2) {
      uint4 pk;
      pk.x = (uint32_t)f2bf(v[k2][0]) | ((uint32_t)f2bf(v[k2][1]) << 16);
      pk.y = (uint32_t)f2bf(v[k2][2]) | ((uint32_t)f2bf(v[k2][3]) << 16);
      pk.z = (uint32_t)f2bf(v[k2][4]) | ((uint32_t)f2bf(v[k2][5]) << 16);
      pk.w = (uint32_t)f2bf(v[k2][6]) | ((uint32_t)f2bf(v[k2][7]) << 16);
      *(uint4*)&Axs[((w * 8 + k2) * 64 + l) * 8] = pk;
    }
  }
  __syncthreads();

#pragma unroll 1
  for (int mt = 0; mt < 8; ++mt) {
    f32x4 acc0 = (f32x4)0.f, acc1 = (f32x4)0.f;
#pragma unroll
    for (int kb = 0; kb < 8; ++kb) {
      bf16x8 av = *(const bf16x8*)&Axs[((mt * 8 + kb) * 64 + l) * 8];
      acc0 = __builtin_amdgcn_mfma_f32_16x16x32_bf16(av, bv[kb][0], acc0, 0, 0, 0);
      acc1 = __builtin_amdgcn_mfma_f32_16x16x32_bf16(av, bv[kb][1], acc1, 0, 0, 0);
    }
#pragma unroll
    for (int r = 0; r < 4; ++r) {
      int t2 = t0 + mt * 16 + g * 4 + r;
      if (t2 < TSTEPS) {
        size_t base = (size_t)t2 * (BATCH * CH) + b * CH;
        cb[base + (w * 2 + 0) * 16 + lm] = f2bf(acc0[r]);
        cb[base + (w * 2 + 1) * 16 + lm] = f2bf(acc1[r]);
      }
    }
  }
}

// ------------------- scan2: overlapped warm-up scan (r11-proven)
__device__ __forceinline__ void scan2_step(
    int t, bool pref, bool doout, const uint16_t* Yr, uint16_t* Yw,
    const uint16_t* __restrict__ cb, uint16_t* __restrict__ yb,
    const bf16x8 af[8][4], ushort* cc, int w, int lm, int g, int tid) {
  bf16x8 yv[8];
#pragma unroll
  for (int kb = 0; kb < 8; ++kb)
    yv[kb] = *(const bf16x8*)&Yr[lm * YROW + kb * 32 + g * 8];
  f32x4 acc[4];
#pragma unroll
  for (int ntl = 0; ntl < 4; ++ntl)
#pragma unroll
    for (int r = 0; r < 4; ++r)
      acc[ntl][r] = bfu(((uint32_t)cc[ntl * 4 + r]) << 16);
  if (pref) {  // c_{t+2} into same regs (2 steps of slack)
    size_t cbase = (size_t)(t + 2) * (BATCH * CH);
#pragma unroll
    for (int ntl = 0; ntl < 4; ++ntl)
#pragma unroll
      for (int r = 0; r < 4; ++r)
        cc[ntl * 4 + r] = cb[cbase + (g * 4 + r) * CH + (w * 4 + ntl) * 16 + lm];
  }
#pragma unroll
  for (int ntl = 0; ntl < 4; ++ntl) {
#pragma unroll
    for (int kb = 0; kb < 8; ++kb)
      acc[ntl] = __builtin_amdgcn_mfma_f32_16x16x32_bf16(yv[kb], af[kb][ntl], acc[ntl], 0, 0, 0);
  }
  uint16_t hbv[16];
#pragma unroll
  for (int ntl = 0; ntl < 4; ++ntl)
#pragma unroll
    for (int r = 0; r < 4; ++r) {
      float v = acc[ntl][r];
      int bb = g * 4 + r, o = (w * 4 + ntl) * 16 + lm;
      uint16_t hb = f2bf(v);
      hbv[ntl * 4 + r] = hb;
      Yw[bb * YROW + o] = hb;
    }
  if (doout) {  // fragment-contiguous y (2 coalesced uint4; fly over barrier)
    uint4 p0, p1;
    p0.x = (uint32_t)hbv[0] | ((uint32_t)hbv[1] << 16);
    p0.y = (uint32_t)hbv[2] | ((uint32_t)hbv[3] << 16);
    p0.z = (uint32_t)hbv[4] | ((uint32_t)hbv[5] << 16);
    p0.w = (uint32_t)hbv[6] | ((uint32_t)hbv[7] << 16);
    p1.x = (uint32_t)hbv[8] | ((uint32_t)hbv[9] << 16);
    p1.y = (uint32_t)hbv[10] | ((uint32_t)hbv[11] << 16);
    p1.z = (uint32_t)hbv[12] | ((uint32_t)hbv[13] << 16);
    p1.w = (uint32_t)hbv[14] | ((uint32_t)hbv[15] << 16);
    uint4* dst = (uint4*)&yb[(size_t)t * 4096 + tid * 16];
    dst[0] = p0;
    dst[1] = p1;
  }
  asm volatile("s_waitcnt lgkmcnt(0)" ::: "memory");
  __builtin_amdgcn_sched_barrier(0);
  __builtin_amdgcn_s_barrier();
  __builtin_amdgcn_sched_barrier(0);
}

__global__ __launch_bounds__(TPB, 2) void k_scan2(
    const uint16_t* __restrict__ Afrag, const uint16_t* __restrict__ cb,
    uint16_t* __restrict__ yb, const float* __restrict__ x) {
  __shared__ __align__(16) uint16_t Y[2][16 * YROW];
  int tid = threadIdx.x;
  int j = blockIdx.x;
  int w = tid >> 6, l = tid & 63;
  int lm = l & 15, g = l >> 4;

  bf16x8 af[8][4];
#pragma unroll
  for (int kb = 0; kb < 8; ++kb)
#pragma unroll
    for (int ntl = 0; ntl < 4; ++ntl) {
      int nt = w * 4 + ntl;
      af[kb][ntl] = *(const bf16x8*)&Afrag[(((size_t)(kb * 16 + nt) * 64) + l) * 8];
    }

  int tstart   = (j == 0) ? 0 : OUT_L * j - WARM;
  int outstart = OUT_L * j;
  int tend     = min(OUT_L * (j + 1), TSTEPS);

  if (j == 0) {  // exact init: Y = x[:,:,0]
    int b = tid >> 4, o0 = (tid & 15) * 16;
#pragma unroll
    for (int q = 0; q < 16; ++q)
      Y[0][b * YROW + o0 + q] = f2bf(x[(size_t)(b * CH + o0 + q) * NEL]);
  } else {
    for (int q = tid; q < 16 * YROW; q += TPB) Y[0][q] = 0;
  }

  ushort c0[16], c1[16];
  {  // prologue: c at tstart, tstart+1
#pragma unroll
    for (int ntl = 0; ntl < 4; ++ntl)
#pragma unroll
      for (int r = 0; r < 4; ++r) {
        size_t off = (size_t)(g * 4 + r) * CH + (w * 4 + ntl) * 16 + lm;
        c0[ntl * 4 + r] = cb[(size_t)tstart * (BATCH * CH) + off];
        c1[ntl * 4 + r] = cb[(size_t)(tstart + 1) * (BATCH * CH) + off];
      }
  }
  __syncthreads();

#pragma unroll 1
  for (int ii = 0; ii < OUT_L + WARM + 2; ii += 2) {
    int t = tstart + ii;
    if (t >= tend) break;
    scan2_step(t, t + 2 < tend, t >= outstart, Y[0], Y[1], cb, yb,
               af, c0, w, lm, g, tid);
    if (t + 1 >= tend) break;
    scan2_step(t + 1, t + 3 < tend, t + 1 >= outstart, Y[1], Y[0], cb, yb,
               af, c1, w, lm, g, tid);
  }
}

// ------------------- yout v3 (r12-proven): OUT-ALIGNED blocks -> out f32
__global__ __launch_bounds__(TPB) void k_yout(const uint16_t* __restrict__ yb,
                                              float* __restrict__ out) {
  __shared__ __align__(16) uint16_t t2[256 * 72];  // 36.9KB
  int bid = blockIdx.x;
  int tb = bid >> 4, sub = bid & 15;
  int G = sub >> 2, wS = sub & 3;
  int t0 = tb * 64;  // OUT index base (aligned); 124*64 = 7936 exact cover
  int tid = threadIdx.x;
  {  // load: row tl holds y[t0+tl-1]; scatter u16 into [col][t]
    int tl = tid >> 2, part = tid & 3;
    int ty = t0 + tl - 1;
    if (ty >= 0) {
      const uint16_t* src =
          &yb[(size_t)ty * 4096 + (wS * 64 + G * 16) * 16 + part * 64];
#pragma unroll
      for (int i = 0; i < 8; ++i) {
        uint4 vv = *(const uint4*)&src[i * 8];
        uint32_t uu[4] = {vv.x, vv.y, vv.z, vv.w};
        int colb = part * 64 + i * 8;
#pragma unroll
        for (int e = 0; e < 4; ++e) {
          t2[(colb + 2 * e) * 72 + tl]     = (uint16_t)(uu[e] & 0xffffu);
          t2[(colb + 2 * e + 1) * 72 + tl] = (uint16_t)(uu[e] >> 16);
        }
      }
    }
  }
  __syncthreads();
  {  // store: thread -> one (b,o); out[t0+q] = y[t0+q-1] = t2[col][q]; aligned
    int b = G * 4 + (tid >> 6);
    int o = wS * 64 + (tid & 63);
    int col = (o & 15) * 16 + ((o >> 4) & 3) * 4 + (b & 3);
    float* dst = &out[(size_t)(b * CH + o) * NEL + t0];
#pragma unroll
    for (int k4 = 0; k4 < 4; ++k4) {
      uint4 v0 = *(const uint4*)&t2[col * 72 + k4 * 16];
      uint4 v1 = *(const uint4*)&t2[col * 72 + k4 * 16 + 8];
      uint32_t uu[8] = {v0.x, v0.y, v0.z, v0.w, v1.x, v1.y, v1.z, v1.w};
      float f[16];
#pragma unroll
      for (int e = 0; e < 8; ++e) {
        f[2 * e]     = bfu(uu[e] << 16);
        f[2 * e + 1] = bfu(uu[e] & 0xffff0000u);
      }
      if (tb == 0 && k4 == 0) {  // skip out idx 0 (edges wrote x0)
#pragma unroll
        for (int e = 1; e < 16; ++e) dst[e] = f[e];
      } else {
#pragma unroll
        for (int m = 0; m < 4; ++m)
          *(float4*)&dst[k4 * 16 + m * 4] =
              make_float4(f[4 * m], f[4 * m + 1], f[4 * m + 2], f[4 * m + 3]);
      }
    }
  }
}

// ======================= fallback path (round-1, proven) =====================
__global__ __launch_bounds__(TPB) void k_cgemm_v(const float* __restrict__ x,
                                                 const uint16_t* __restrict__ W1b,
                                                 float* __restrict__ out) {
  __shared__ __align__(16) uint16_t w1[CH * 128];
  __shared__ __align__(16) float xs[32][128];
  int tid = threadIdx.x;
  int bid = blockIdx.x;
  int b = bid / (TTILES * 2);
  int rem = bid % (TTILES * 2);
  int ttile = rem >> 1, otile = rem & 1;
  int t0 = ttile * 128, o0 = otile * 128;
  int tx = tid & 15, ty = tid >> 4;
  int o8 = o0 + tx * 8;
  int tb = t0 + ty * 8;
  {
    uint4* dst = (uint4*)w1;
    for (int q = tid; q < CH * 128 / 8; q += TPB) {
      int row = q >> 4, seg = q & 15;
      dst[q] = *(const uint4*)&W1b[row * CH + o0 + seg * 8];
    }
  }
  float acc[8][8];
#pragma unroll
  for (int i = 0; i < 8; ++i)
#pragma unroll
    for (int j = 0; j < 8; ++j) acc[i][j] = 0.f;
  for (int c0 = 0; c0 < CH; c0 += 32) {
    __syncthreads();
#pragma unroll
    for (int kk = 0; kk < 4; ++kk) {
      int q = tid + kk * TPB;
      int cc = q >> 5, tf = (q & 31) * 4;
      *(float4*)&xs[cc][tf] =
          *(const float4*)&x[(size_t)(b * CH + c0 + cc) * NEL + t0 + NDIL + tf];
    }
    __syncthreads();
#pragma unroll 4
    for (int cc = 0; cc < 32; ++cc) {
      float4 xa = *(const float4*)&xs[cc][ty * 8];
      float4 xb = *(const float4*)&xs[cc][ty * 8 + 4];
      float xv[8] = {xa.x, xa.y, xa.z, xa.w, xb.x, xb.y, xb.z, xb.w};
      uint4 wv = *(const uint4*)&w1[(c0 + cc) * 128 + tx * 8];
      float wf[8] = {bfu(wv.x << 16), bfu(wv.x & 0xffff0000u),
                     bfu(wv.y << 16), bfu(wv.y & 0xffff0000u),
                     bfu(wv.z << 16), bfu(wv.z & 0xffff0000u),
                     bfu(wv.w << 16), bfu(wv.w & 0xffff0000u)};
#pragma unroll
      for (int i = 0; i < 8; ++i)
#pragma unroll
        for (int j = 0; j < 8; ++j) acc[i][j] += xv[i] * wf[j];
    }
  }
#pragma unroll
  for (int j = 0; j < 8; ++j) {
    size_t base = (size_t)(b * CH + o8 + j) * NEL + tb + 1;
#pragma unroll
    for (int i = 0; i < 8; ++i)
      if (tb + i < TSTEPS) out[base + i] = acc[i][j];
  }
}

template <bool PH3>
__global__ __launch_bounds__(TPB) void k_scan(const uint16_t* __restrict__ Ab,
                                              const float* __restrict__ initbuf,
                                              float* __restrict__ Ebuf,
                                              float* __restrict__ out) {
  __shared__ __align__(16) uint16_t Al[CH * CH];
  __shared__ __align__(16) float yl[BATCH * YPAD];
  int tid = threadIdx.x;
  int j = blockIdx.x;
  {
    const uint4* src = (const uint4*)Ab;
    uint4* dst = (uint4*)Al;
    for (int q = tid; q < CH * CH / 8; q += TPB) dst[q] = src[q];
  }
  if constexpr (PH3) {
    for (int q = tid; q < BATCH * CH / 4; q += TPB) {
      int b = q >> 6, c4 = (q & 63) * 4;
      *(float4*)&yl[b * YPAD + c4] =
          *(const float4*)&initbuf[(size_t)j * BATCH * CH + b * CH + c4];
    }
  } else {
    for (int q = tid; q < BATCH * YPAD; q += TPB) yl[q] = 0.f;
  }
  __syncthreads();
  int o4 = (tid & 63) * 4;
  int b4 = (tid >> 6) * 4;
  int len = min(LCH, TSTEPS - j * LCH);
  float acc[4][4];
  for (int i = 0; i < len; ++i) {
    int t = j * LCH + i;
    float cv[4][4];
#pragma unroll
    for (int bb = 0; bb < 4; ++bb)
#pragma unroll
      for (int oo = 0; oo < 4; ++oo)
        cv[bb][oo] = out[(size_t)((b4 + bb) * CH + o4 + oo) * NEL + t + 1];
#pragma unroll
    for (int bb = 0; bb < 4; ++bb)
#pragma unroll
      for (int oo = 0; oo < 4; ++oo) acc[bb][oo] = 0.f;
#pragma unroll 2
    for (int c = 0; c < CH; c += 4) {
      float4 v0 = *(const float4*)&yl[(b4 + 0) * YPAD + c];
      float4 v1 = *(const float4*)&yl[(b4 + 1) * YPAD + c];
      float4 v2 = *(const float4*)&yl[(b4 + 2) * YPAD + c];
      float4 v3 = *(const float4*)&yl[(b4 + 3) * YPAD + c];
      float y0[4] = {v0.x, v0.y, v0.z, v0.w};
      float y1[4] = {v1.x, v1.y, v1.z, v1.w};
      float y2[4] = {v2.x, v2.y, v2.z, v2.w};
      float y3[4] = {v3.x, v3.y, v3.z, v3.w};
#pragma unroll
      for (int k = 0; k < 4; ++k) {
        uint2 au = *(const uint2*)&Al[(c + k) * CH + o4];
        float a[4] = {bfu(au.x << 16), bfu(au.x & 0xffff0000u),
                      bfu(au.y << 16), bfu(au.y & 0xffff0000u)};
#pragma unroll
        for (int oo = 0; oo < 4; ++oo) {
          acc[0][oo] += y0[k] * a[oo];
          acc[1][oo] += y1[k] * a[oo];
          acc[2][oo] += y2[k] * a[oo];
          acc[3][oo] += y3[k] * a[oo];
        }
      }
    }
#pragma unroll
    for (int bb = 0; bb < 4; ++bb)
#pragma unroll
      for (int oo = 0; oo < 4; ++oo) acc[bb][oo] += cv[bb][oo];
    __syncthreads();
#pragma unroll
    for (int bb = 0; bb < 4; ++bb)
      *(float4*)&yl[(b4 + bb) * YPAD + o4] =
          make_float4(acc[bb][0], acc[bb][1], acc[bb][2], acc[bb][3]);
    if constexpr (PH3) {
#pragma unroll
      for (int bb = 0; bb < 4; ++bb)
#pragma unroll
        for (int oo = 0; oo < 4; ++oo)
          out[(size_t)((b4 + bb) * CH + o4 + oo) * NEL + t + 1] = acc[bb][oo];
    }
    __syncthreads();
  }
  if constexpr (!PH3) {
#pragma unroll
    for (int bb = 0; bb < 4; ++bb)
#pragma unroll
      for (int oo = 0; oo < 4; ++oo)
        Ebuf[(size_t)j * BATCH * CH + (b4 + bb) * CH + o4 + oo] = acc[bb][oo];
  }
}

__global__ __launch_bounds__(TPB) void k_phase2(const float* __restrict__ ALf,
                                                const float* __restrict__ Ebuf,
                                                float* __restrict__ initbuf) {
  __shared__ __align__(16) uint16_t At[CH * A2PAD];
  __shared__ __align__(16) float st[CH];
  int b = blockIdx.x, tid = threadIdx.x;
  for (int q = tid; q < CH * CH; q += TPB) {
    int c = q >> 8, o = q & 255;
    At[o * A2PAD + c] = f2bf(ALf[q]);
  }
  st[tid] = initbuf[b * CH + tid];
  __syncthreads();
  for (int jj = 1; jj < NCH; ++jj) {
    float acc = Ebuf[(size_t)(jj - 1) * BATCH * CH + b * CH + tid];
#pragma unroll 4
    for (int c = 0; c < CH; c += 8) {
      uint4 au = *(const uint4*)&At[tid * A2PAD + c];
      float4 s0 = *(const float4*)&st[c];
      float4 s1 = *(const float4*)&st[c + 4];
      acc += bfu(au.x << 16) * s0.x + bfu(au.x & 0xffff0000u) * s0.y +
             bfu(au.y << 16) * s0.z + bfu(au.y & 0xffff0000u) * s0.w +
             bfu(au.z << 16) * s1.x + bfu(au.z & 0xffff0000u) * s1.y +
             bfu(au.w << 16) * s1.z + bfu(au.w & 0xffff0000u) * s1.w;
    }
    __syncthreads();
    st[tid] = acc;
    initbuf[(size_t)jj * BATCH * CH + b * CH + tid] = acc;
    __syncthreads();
  }
}

// ============================================================================
extern "C" void kernel_launch(void* const* d_in, const int* in_sizes, int n_in,
                              void* d_out, int out_size, void* d_ws, size_t ws_size,
                              hipStream_t stream) {
  const float* x = (const float*)d_in[0];
  const float* w = (const float*)d_in[1];
  float* out = (float*)d_out;
  char* ws = (char*)d_ws;

  float*    Af    = (float*)(ws + OFF_AF);
  float*    P1    = (float*)(ws + OFF_P1);
  float*    P2    = (float*)(ws + OFF_P2);
  uint16_t* Ab    = (uint16_t*)(ws + OFF_AB16);
  uint16_t* W1b   = (uint16_t*)(ws + OFF_W1B);
  float*    Ebuf  = (float*)(ws + OFF_E);
  float*    inb   = (float*)(ws + OFF_INIT);
  uint16_t* Afrag = (uint16_t*)(ws + OFF_AFRAG);
  uint16_t* W1f   = (uint16_t*)(ws + OFF_W1FR);
  uint16_t* cbuf  = (uint16_t*)(ws + OFF_CBUF);
  uint16_t* ybuf  = (uint16_t*)(ws + OFF_YBUF);

  const bool fast = ws_size >= WS_NEED;

  k_prep<<<CH, CH, 0, stream>>>(w, Af, Ab, W1b, fast ? Afrag : nullptr, W1f);
  if (fast) {
    k_edges<<<BATCH * CH, 256, 0, stream>>>(x, out);
    k_cgemm_m<<<BATCH * TTILES, 512, 0, stream>>>(x, W1f, cbuf);
    k_scan2<<<NCH2, TPB, 0, stream>>>(Afrag, cbuf, ybuf, x);
    k_yout<<<124 * 16, TPB, 0, stream>>>(ybuf, out);
  } else {
    k_edges<<<BATCH * CH, 256, 0, stream>>>(x, out);
    k_init0<<<BATCH, CH, 0, stream>>>(x, inb);
    k_sqmm<<<CH, TPB, 0, stream>>>(Af, P1);   // A^2
    k_sqmm<<<CH, TPB, 0, stream>>>(P1, P2);   // A^4
    k_sqmm<<<CH, TPB, 0, stream>>>(P2, P1);   // A^8
    k_sqmm<<<CH, TPB, 0, stream>>>(P1, P2);   // A^16 (= A^LCH)
    k_cgemm_v<<<BATCH * TTILES * 2, TPB, 0, stream>>>(x, W1b, out);
    k_scan<false><<<NCH - 1, TPB, 0, stream>>>(Ab, nullptr, Ebuf, out);
    k_phase2<<<BATCH, TPB, 0, stream>>>(P2, Ebuf, inb);
    k_scan<true><<<NCH, TPB, 0, stream>>>(Ab, inb, nullptr, out);
  }
}